// Round 14
// baseline (512.329 us; speedup 1.0000x reference)
//
#include <hip/hip_runtime.h>
#include <cstdint>
#include <cstddef>

#define B_   8
#define N_   2048
#define D_   1024
#define DK_  256
#define M_   (B_ * N_)   // 16384
#define TOPK 32
#define NDIG 5

typedef unsigned short ushort_t;
typedef float  fvec4 __attribute__((ext_vector_type(4)));
typedef short  bvec8 __attribute__((ext_vector_type(8)));   // 8 bf16 (bits)
typedef float  avec4 __attribute__((ext_vector_type(4)));   // f32 MFMA acc
typedef int    ivec4 __attribute__((ext_vector_type(4)));   // 16B chunks / i32 acc

__device__ inline ushort_t f32_to_bf16_rn(float f) {
  unsigned u = __float_as_uint(f);
  u += 0x7fffu + ((u >> 16) & 1u);
  return (ushort_t)(u >> 16);
}
__device__ inline float bf16_to_f32(ushort_t u) {
  return __uint_as_float(((unsigned)u) << 16);
}
__device__ inline unsigned bf16_key(ushort_t h) {   // monotone 16-bit key
  return (h & 0x8000u) ? (unsigned)((~h) & 0xFFFFu) : (unsigned)(h | 0x8000u);
}
__device__ inline float key_to_f32(unsigned k) {    // exact inverse
  const ushort_t h = (k & 0x8000u) ? (ushort_t)(k ^ 0x8000u)
                                   : (ushort_t)((~k) & 0xFFFFu);
  return bf16_to_f32(h);
}

// ==========================================================================
// OZAKI PATH (r13, proven): exact integer decomposition on the i8 pipe.
// ==========================================================================
__global__ __launch_bounds__(256) void split_x_kernel(
    const float* __restrict__ X, signed char* __restrict__ Xdig)
{
  const size_t MK = (size_t)M_ * D_;
  const int total = (int)(MK / 4);
  for (int idx = blockIdx.x * 256 + threadIdx.x; idx < total;
       idx += gridDim.x * 256) {
    const fvec4 x = ((const fvec4*)X)[idx];
    unsigned pack[NDIG] = {0u, 0u, 0u, 0u, 0u};
#pragma unroll
    for (int e = 0; e < 4; e++) {
      float s = x[e] * 0.0625f * 128.f;
#pragma unroll
      for (int d = 0; d < NDIG; d++) {
        const float a = rintf(s);
        s = (s - a) * 128.f;
        pack[d] |= ((unsigned)((int)a & 0xff)) << (e * 8);
      }
    }
#pragma unroll
    for (int d = 0; d < NDIG; d++)
      ((unsigned*)(Xdig + (size_t)d * MK))[idx] = pack[d];
  }
}

__global__ __launch_bounds__(256) void split_w_kernel(
    const float* __restrict__ Wq, const float* __restrict__ Wk,
    signed char* __restrict__ Wdig)
{
  const size_t WK = (size_t)512 * 1024;
  const int cc = blockIdx.x;
  const float* Wp = (cc < 256) ? Wq : Wk;
  const int c = cc & 255;
  const int k0 = threadIdx.x * 4;
  unsigned pack[NDIG] = {0u, 0u, 0u, 0u, 0u};
#pragma unroll
  for (int e = 0; e < 4; e++) {
    float s = Wp[(size_t)(k0 + e) * DK_ + c] * 16.f * 128.f;
#pragma unroll
    for (int d = 0; d < NDIG; d++) {
      const float a = rintf(s);
      s = (s - a) * 128.f;
      pack[d] |= ((unsigned)((int)a & 0xff)) << (e * 8);
    }
  }
#pragma unroll
  for (int d = 0; d < NDIG; d++)
    ((unsigned*)(Wdig + (size_t)d * WK + (size_t)cc * 1024))[threadIdx.x] = pack[d];
}

__global__ __launch_bounds__(512) void ozaki_gemm_kernel(
    const signed char* __restrict__ Xdig, const signed char* __restrict__ Wdig,
    const float* __restrict__ bq, const float* __restrict__ bk,
    double* __restrict__ Qd, double* __restrict__ Kd,
    ushort_t* __restrict__ Qbf, ushort_t* __restrict__ Kbf)
{
  __shared__ __align__(16) char L[61440];
  const int tid  = threadIdx.x;
  const int lane = tid & 63;
  const int w    = tid >> 6;
  const int wm   = (w >> 2) * 32;
  const int wc   = (w & 3) * 32;
  const int m0   = blockIdx.y * 64;
  const int c0   = blockIdx.x * 128;
  const size_t MK = (size_t)M_ * D_;
  const size_t WK = (size_t)512 * 1024;

  ivec4 acc[NDIG][2][2];
#pragma unroll
  for (int s = 0; s < NDIG; s++)
#pragma unroll
    for (int mi = 0; mi < 2; mi++)
#pragma unroll
      for (int nj = 0; nj < 2; nj++) acc[s][mi][nj] = (ivec4)(0);

  for (int k0 = 0; k0 < D_; k0 += 64) {
    for (int c = tid; c < 1280; c += 512) {
      const int d = c >> 8, rem = c & 255, r = rem >> 2, kp = rem & 3;
      const ivec4 raw = *(const ivec4*)(Xdig + (size_t)d * MK +
                         (size_t)(m0 + r) * D_ + k0 + kp * 16);
      *(ivec4*)&L[d * 4096 + r * 64 + ((kp ^ (r & 3)) << 4)] = raw;
    }
    for (int c = tid; c < 2560; c += 512) {
      const int d = c >> 9, rem = c & 511, r = rem >> 2, kp = rem & 3;
      const ivec4 raw = *(const ivec4*)(Wdig + (size_t)d * WK +
                         (size_t)(c0 + r) * 1024 + k0 + kp * 16);
      *(ivec4*)&L[20480 + d * 8192 + r * 64 + ((kp ^ (r & 3)) << 4)] = raw;
    }
    __syncthreads();

    ivec4 afr[2][NDIG];
#pragma unroll
    for (int mi = 0; mi < 2; mi++) {
      const int r = wm + mi * 16 + (lane & 15);
      const int sl = (((lane >> 4) ^ (r & 3)) << 4);
#pragma unroll
      for (int d = 0; d < NDIG; d++)
        afr[mi][d] = *(const ivec4*)&L[d * 4096 + r * 64 + sl];
    }
#pragma unroll
    for (int nj = 0; nj < 2; nj++) {
      const int rc = wc + nj * 16 + (lane & 15);
      const int sl = (((lane >> 4) ^ (rc & 3)) << 4);
#pragma unroll
      for (int jd = 0; jd < NDIG; jd++) {
        const ivec4 bfr = *(const ivec4*)&L[20480 + jd * 8192 + rc * 64 + sl];
#pragma unroll
        for (int id = 0; id + jd < NDIG; id++)
#pragma unroll
          for (int mi = 0; mi < 2; mi++)
            acc[id + jd][mi][nj] = __builtin_amdgcn_mfma_i32_16x16x64_i8(
                afr[mi][id], bfr, acc[id + jd][mi][nj], 0, 0, 0);
      }
    }
    __syncthreads();
  }

  const double SCL[NDIG] = {0x1p-14, 0x1p-21, 0x1p-28, 0x1p-35, 0x1p-42};
#pragma unroll
  for (int nj = 0; nj < 2; nj++) {
    const int c = c0 + wc + nj * 16 + (lane & 15);
    const bool isQ = (c < 256);
    const int cw = isQ ? c : (c - 256);
    const double bias = (double)(isQ ? bq[cw] : bk[cw]);
#pragma unroll
    for (int mi = 0; mi < 2; mi++) {
#pragma unroll
      for (int ri = 0; ri < 4; ri++) {
        const int m = m0 + wm + mi * 16 + (lane >> 4) * 4 + ri;
        double val = bias;
#pragma unroll
        for (int s = 0; s < NDIG; s++)
          val += (double)acc[s][mi][nj][ri] * SCL[s];
        const size_t off = (size_t)m * DK_ + cw;
        if (isQ) { Qd[off] = val; Qbf[off] = f32_to_bf16_rn((float)val); }
        else     { Kd[off] = val; Kbf[off] = f32_to_bf16_rn((float)val); }
      }
    }
  }
}

// ==========================================================================
// FALLBACK proj (r5, proven) — unchanged.
// ==========================================================================
__global__ __launch_bounds__(256) void proj_kernel(
    const float* __restrict__ X, const float* __restrict__ Wq,
    const float* __restrict__ bq, const float* __restrict__ Wk,
    const float* __restrict__ bk, double* __restrict__ Qd,
    double* __restrict__ Kd, ushort_t* __restrict__ Qbf,
    ushort_t* __restrict__ Kbf)
{
  __shared__ float As[16][132];
  __shared__ float Bs[16][132];
  const int tid = threadIdx.x;
  const int tx = tid & 15;
  const int ty = tid >> 4;
  const int m0 = blockIdx.y * 128;
  const int j0 = blockIdx.x * 128;
  const bool isQ = (j0 < 256);
  const float* Wp = isQ ? Wq : Wk;
  const float* bp = isQ ? bq : bk;
  const int jw = isQ ? j0 : (j0 - 256);

  double acc[8][8];
#pragma unroll
  for (int i = 0; i < 8; i++)
#pragma unroll
    for (int j = 0; j < 8; j++) acc[i][j] = 0.0;

  for (int k0 = 0; k0 < D_; k0 += 16) {
    {
      const int r = tid >> 2, k4 = (tid & 3) * 4;
#pragma unroll
      for (int p = 0; p < 2; p++) {
        const int m = r + 64 * p;
        const fvec4 v = *(const fvec4*)&X[(size_t)(m0 + m) * D_ + k0 + k4];
#pragma unroll
        for (int c = 0; c < 4; c++) As[k4 + c][m] = v[c];
      }
    }
    {
      const int k = tid >> 4, j8 = (tid & 15) * 8;
      const fvec4 v0 = *(const fvec4*)&Wp[(size_t)(k0 + k) * DK_ + jw + j8];
      const fvec4 v1 = *(const fvec4*)&Wp[(size_t)(k0 + k) * DK_ + jw + j8 + 4];
      *(fvec4*)&Bs[k][j8]     = v0;
      *(fvec4*)&Bs[k][j8 + 4] = v1;
    }
    __syncthreads();
#pragma unroll
    for (int kk = 0; kk < 16; kk++) {
      const fvec4 a0 = *(const fvec4*)&As[kk][ty * 8];
      const fvec4 a1 = *(const fvec4*)&As[kk][ty * 8 + 4];
      const fvec4 b0 = *(const fvec4*)&Bs[kk][tx * 8];
      const fvec4 b1 = *(const fvec4*)&Bs[kk][tx * 8 + 4];
      double a[8], b[8];
#pragma unroll
      for (int i = 0; i < 4; i++) {
        a[i] = (double)a0[i]; a[i + 4] = (double)a1[i];
        b[i] = (double)b0[i]; b[i + 4] = (double)b1[i];
      }
#pragma unroll
      for (int i = 0; i < 8; i++)
#pragma unroll
        for (int j = 0; j < 8; j++)
          acc[i][j] = fma(a[i], b[j], acc[i][j]);
    }
    __syncthreads();
  }

#pragma unroll
  for (int i = 0; i < 8; i++) {
    const int m = m0 + ty * 8 + i;
#pragma unroll
    for (int j = 0; j < 8; j++) {
      const int c = jw + tx * 8 + j;
      const double v = acc[i][j] + (double)bp[c];
      const size_t off = (size_t)m * DK_ + c;
      if (isQ) { Qd[off] = v; if (Qbf) Qbf[off] = f32_to_bf16_rn((float)v); }
      else     { Kd[off] = v; if (Kbf) Kbf[off] = f32_to_bf16_rn((float)v); }
    }
  }
}

// ==========================================================================
// scores via bf16 MFMA (proven) — unchanged.
// ==========================================================================
__global__ __launch_bounds__(256) void score_bf16_kernel(
    const ushort_t* __restrict__ Qb, const ushort_t* __restrict__ Kb,
    float* __restrict__ outf, ushort_t* __restrict__ outbf)
{
  __shared__ ushort_t Asl[128 * 40];
  __shared__ ushort_t Bsl[128 * 40];
  const int tid = threadIdx.x;
  const int b  = blockIdx.z;
  const int q0 = blockIdx.y * 128;
  const int m0 = blockIdx.x * 128;
  const int w = tid >> 6, lane = tid & 63;
  const int wq = (w >> 1) * 64, wm = (w & 1) * 64;
  const int rsel = lane & 15, ksel = (lane >> 4) * 8;

  avec4 acc[4][4];
#pragma unroll
  for (int i = 0; i < 4; i++)
#pragma unroll
    for (int j = 0; j < 4; j++) acc[i][j] = (avec4)(0.f);

  for (int k0 = 0; k0 < DK_; k0 += 32) {
#pragma unroll
    for (int cc = 0; cc < 2; cc++) {
      const int c = tid + cc * 256;
      const int r = c >> 2, part = c & 3;
      const ivec4 va = *(const ivec4*)&Qb[((size_t)b * N_ + q0 + r) * DK_ + k0 + part * 8];
      const ivec4 vb = *(const ivec4*)&Kb[((size_t)b * N_ + m0 + r) * DK_ + k0 + part * 8];
      *(ivec4*)&Asl[r * 40 + part * 8] = va;
      *(ivec4*)&Bsl[r * 40 + part * 8] = vb;
    }
    __syncthreads();
    bvec8 aF[4], bF[4];
#pragma unroll
    for (int mi = 0; mi < 4; mi++)
      aF[mi] = *(const bvec8*)&Asl[(wq + mi * 16 + rsel) * 40 + ksel];
#pragma unroll
    for (int nj = 0; nj < 4; nj++)
      bF[nj] = *(const bvec8*)&Bsl[(wm + nj * 16 + rsel) * 40 + ksel];
#pragma unroll
    for (int mi = 0; mi < 4; mi++)
#pragma unroll
      for (int nj = 0; nj < 4; nj++)
        acc[mi][nj] = __builtin_amdgcn_mfma_f32_16x16x32_bf16(
            aF[mi], bF[nj], acc[mi][nj], 0, 0, 0);
    __syncthreads();
  }

#pragma unroll
  for (int mi = 0; mi < 4; mi++)
#pragma unroll
    for (int nj = 0; nj < 4; nj++)
#pragma unroll
      for (int r = 0; r < 4; r++) {
        const int row = q0 + wq + mi * 16 + (lane >> 4) * 4 + r;
        const int col = m0 + wm + nj * 16 + (lane & 15);
        const size_t off = ((size_t)b * N_ + row) * N_ + col;
        const float v = acc[mi][nj][r] * 0.0625f;
        if (outbf) outbf[off] = f32_to_bf16_rn(v);
        else       outf[off] = v;
      }
}

// f32 scores from f64 (deep fallback) — unchanged.
__global__ __launch_bounds__(256) void score_f64_kernel(
    const double* __restrict__ Qd, const double* __restrict__ Kd,
    float* __restrict__ out)
{
  __shared__ float As[16][68];
  __shared__ float Bs[16][68];
  const int tid = threadIdx.x;
  const int tx = tid & 15, ty = tid >> 4;
  const int b  = blockIdx.z;
  const int q0 = blockIdx.y * 64;
  const int m0 = blockIdx.x * 64;
  const size_t rowbase = (size_t)b * N_;

  float acc[4][4];
#pragma unroll
  for (int i = 0; i < 4; i++)
#pragma unroll
    for (int j = 0; j < 4; j++) acc[i][j] = 0.f;

  for (int k0 = 0; k0 < DK_; k0 += 16) {
    const int mt = tid >> 4, kt = tid & 15;
#pragma unroll
    for (int p = 0; p < 4; p++) {
      const int m = mt + 16 * p;
      As[kt][m] = (float)Qd[(rowbase + q0 + m) * DK_ + k0 + kt];
      Bs[kt][m] = (float)Kd[(rowbase + m0 + m) * DK_ + k0 + kt];
    }
    __syncthreads();
#pragma unroll
    for (int kk = 0; kk < 16; kk++) {
      float a[4], bb[4];
#pragma unroll
      for (int i = 0; i < 4; i++) a[i] = As[kk][ty * 4 + i];
#pragma unroll
      for (int j = 0; j < 4; j++) bb[j] = Bs[kk][tx * 4 + j];
#pragma unroll
      for (int i = 0; i < 4; i++)
#pragma unroll
        for (int j = 0; j < 4; j++)
          acc[i][j] = fmaf(a[i], bb[j], acc[i][j]);
    }
    __syncthreads();
  }

#pragma unroll
  for (int i = 0; i < 4; i++) {
    const size_t r = (size_t)b * N_ + q0 + ty * 4 + i;
#pragma unroll
    for (int j = 0; j < 4; j++)
      out[r * N_ + m0 + tx * 4 + j] = acc[i][j] * 0.0625f;
  }
}

// ==========================================================================
// NEW topk (oz path): register-resident binary-search selection, no atics
// histogram, no full-row write (out pre-zeroed by hipMemsetAsync; scatter 32
// weights). f64 rescore/rank identical to r13 => same selection.
// Row swizzle: XCD x handles batch x (Kd 4MB fits one XCD L2).
// ==========================================================================
__global__ __launch_bounds__(256) void topk_scatter_kernel(
    float* __restrict__ out, const ushort_t* __restrict__ sbf,
    const double* __restrict__ Qd, const double* __restrict__ Kd,
    float margin)
{
  const int bid = blockIdx.x;
  const int row = (bid & 7) * 2048 + (bid >> 3);   // batch-per-XCD locality
  const int b   = row >> 11;
  const int tid = threadIdx.x;
  const int lane = tid & 63, wid = tid >> 6;

  __shared__ double   qrow[DK_];
  __shared__ int      cidx[128];
  __shared__ double   cval[128];
  __shared__ int      cnt_ws[4];
  __shared__ int      ncand_s;
  __shared__ double   wmax[4];
  __shared__ float    wsum[4];

  // ---- load 8 scores into registers (one 16B load) ----
  const ivec4 v = *(const ivec4*)&sbf[(size_t)row * N_ + tid * 8];
  const ushort_t* u = (const ushort_t*)&v;
  unsigned kk[8];
  float    fv[8];
#pragma unroll
  for (int e = 0; e < 8; e++) {
    kk[e] = bf16_key(u[e]);
    fv[e] = bf16_to_f32(u[e]);
  }
  qrow[tid] = Qd[(size_t)row * DK_ + tid];
  if (tid == 0) ncand_s = 0;

  // ---- binary search for 32nd-largest stored key (16 iters, no atomics) --
  unsigned lo = 0, hi = 65535;
#pragma unroll 1
  for (int it = 0; it < 16; it++) {
    const unsigned mid = (lo + hi + 1) >> 1;
    int c = 0;
#pragma unroll
    for (int e = 0; e < 8; e++) c += (kk[e] >= mid);
#pragma unroll
    for (int off = 32; off > 0; off >>= 1) c += __shfl_xor(c, off);
    if (lane == 0) cnt_ws[wid] = c;
    __syncthreads();
    const int tot = cnt_ws[0] + cnt_ws[1] + cnt_ws[2] + cnt_ws[3];
    if (tot >= TOPK) lo = mid; else hi = mid - 1;
    __syncthreads();
  }
  const float cthr = key_to_f32(lo) - margin;   // exact 32nd stored value

  // ---- gather candidates (only ~55 atomics/row) ----
#pragma unroll
  for (int e = 0; e < 8; e++) {
    if (fv[e] >= cthr) {
      const int p = atomicAdd(&ncand_s, 1);
      if (p < 128) cidx[p] = tid * 8 + e;
    }
  }
  __syncthreads();
  int nc = ncand_s;
  if (nc > 128) nc = 128;

  // ---- f64 rescore (identical fma order to r13) ----
  for (int base = 0; base < nc; base += 4) {
    const int c = base + wid;
    if (c < nc) {
      const double* kp = Kd + ((size_t)b * N_ + cidx[c]) * DK_;
      double a = 0.0;
#pragma unroll
      for (int q = 0; q < 4; q++)
        a = fma(qrow[lane * 4 + q], kp[lane * 4 + q], a);
#pragma unroll
      for (int off = 32; off > 0; off >>= 1) a += __shfl_xor(a, off);
      if (lane == 0) cval[c] = a * 0.0625;
    }
  }
  __syncthreads();

  // ---- exact top-32 (value desc, index asc) + softmax + scatter ----
  bool sel = false;
  double vv = 0.0;
  int myidx = 0;
  if (tid < nc) {
    vv = cval[tid];
    myidx = cidx[tid];
    int rank = 0;
    for (int j = 0; j < nc; j++) {
      const double vj = cval[j];
      rank += (vj > vv) || (vj == vv && cidx[j] < myidx);
    }
    sel = (rank < TOPK);
  }
  double mv = (tid < nc) ? vv : -1.0e300;
#pragma unroll
  for (int off = 32; off > 0; off >>= 1) {
    const double o = __shfl_xor(mv, off);
    mv = o > mv ? o : mv;
  }
  if (lane == 0) wmax[wid] = mv;
  __syncthreads();
  const double vmax = max(max(wmax[0], wmax[1]), max(wmax[2], wmax[3]));
  const float ev = sel ? expf((float)(vv - vmax)) : 0.f;
  float es = ev;
#pragma unroll
  for (int off = 32; off > 0; off >>= 1) es += __shfl_xor(es, off);
  if (lane == 0) wsum[wid] = es;
  __syncthreads();
  const float esum = wsum[0] + wsum[1] + wsum[2] + wsum[3];

  if (sel) out[(size_t)row * N_ + myidx] = ev / esum;
}

// ==========================================================================
// FULL topk (fallback tiers; scores may live in `out`) — r13 version.
// ==========================================================================
__global__ __launch_bounds__(256) void topk_softmax_kernel(
    float* __restrict__ out, const ushort_t* __restrict__ sbf,
    const float* __restrict__ sf, const double* __restrict__ Qd,
    const double* __restrict__ Kd, float margin)
{
  const int row = blockIdx.x;
  const int b   = row >> 11;
  const int tid = threadIdx.x;
  float* rowp = out + (size_t)row * N_;

  __shared__ float    s[N_];
  __shared__ double   qrow[DK_];
  __shared__ unsigned hist[256];
  __shared__ unsigned sfx[256];
  __shared__ int      cidx[128];
  __shared__ double   cval[128];
  __shared__ int      ncand_s;
  __shared__ unsigned prefix_s;
  __shared__ int      want_s;
  __shared__ double   wmax[4];
  __shared__ float    wsum[4];

  if (sbf) {
    const ivec4 v = *(const ivec4*)&sbf[(size_t)row * N_ + tid * 8];
    const ushort_t* u = (const ushort_t*)&v;
#pragma unroll
    for (int c = 0; c < 8; c++) s[tid * 8 + c] = bf16_to_f32(u[c]);
  } else {
#pragma unroll
    for (int p = 0; p < 2; p++) {
      const fvec4 v = *(const fvec4*)&sf[(size_t)row * N_ + tid * 8 + p * 4];
#pragma unroll
      for (int c = 0; c < 4; c++) s[tid * 8 + p * 4 + c] = v[c];
    }
  }
  qrow[tid] = Qd[(size_t)row * DK_ + tid];
  __syncthreads();

  unsigned prefix = 0;
  int want = TOPK;
  for (int pass = 0; pass < 2; pass++) {
    hist[tid] = 0;
    __syncthreads();
    const int shift_b = 8 - 8 * pass;
    for (int i = tid; i < N_; i += 256) {
      unsigned uu = __float_as_uint(s[i]);
      uu = (uu & 0x80000000u) ? ~uu : (uu | 0x80000000u);
      const unsigned key = uu >> 16;
      const bool ok = (pass == 0) || ((key >> 8) == prefix);
      if (ok) atomicAdd(&hist[(key >> shift_b) & 255u], 1u);
    }
    __syncthreads();
    sfx[tid] = hist[tid];
    __syncthreads();
    for (int st = 1; st < 256; st <<= 1) {
      const unsigned add = (tid + st < 256) ? sfx[tid + st] : 0u;
      __syncthreads();
      sfx[tid] += add;
      __syncthreads();
    }
    const int gt = (int)(sfx[tid] - hist[tid]);
    if (gt < want && (int)sfx[tid] >= want) {
      prefix_s = (prefix << 8) | (unsigned)tid;
      want_s = want - gt;
    }
    __syncthreads();
    prefix = prefix_s;
    want = want_s;
    __syncthreads();
  }
  const unsigned k16 = prefix;
  unsigned ulo;
  if (k16 & 0x8000u) ulo = (k16 << 16) ^ 0x80000000u;
  else               ulo = ~(k16 << 16);
  const float cthr = __uint_as_float(ulo) - margin;

  if (tid == 0) ncand_s = 0;
  __syncthreads();
  for (int i = tid; i < N_; i += 256) {
    if (s[i] >= cthr) {
      const int p = atomicAdd(&ncand_s, 1);
      if (p < 128) cidx[p] = i;
    }
  }
  __syncthreads();
  int nc = ncand_s;
  if (nc > 128) nc = 128;

  const int wid = tid >> 6, lane = tid & 63;
  for (int base = 0; base < nc; base += 4) {
    const int c = base + wid;
    if (c < nc) {
      const double* kp = Kd + ((size_t)b * N_ + cidx[c]) * DK_;
      double a = 0.0;
#pragma unroll
      for (int q = 0; q < 4; q++)
        a = fma(qrow[lane * 4 + q], kp[lane * 4 + q], a);
#pragma unroll
      for (int off = 32; off > 0; off >>= 1) a += __shfl_xor(a, off);
      if (lane == 0) cval[c] = a * 0.0625;
    }
  }
  __syncthreads();

  bool sel = false;
  double v = 0.0;
  int myidx = 0;
  if (tid < nc) {
    v = cval[tid];
    myidx = cidx[tid];
    int rank = 0;
    for (int j = 0; j < nc; j++) {
      const double vj = cval[j];
      rank += (vj > v) || (vj == v && cidx[j] < myidx);
    }
    sel = (rank < TOPK);
  }
  double mv = (tid < nc) ? v : -1.0e300;
#pragma unroll
  for (int off = 32; off > 0; off >>= 1) {
    const double o = __shfl_xor(mv, off);
    mv = o > mv ? o : mv;
  }
  if (lane == 0) wmax[wid] = mv;
  __syncthreads();
  const double vmax = max(max(wmax[0], wmax[1]), max(wmax[2], wmax[3]));
  const float ev = sel ? expf((float)(v - vmax)) : 0.f;
  float es = ev;
#pragma unroll
  for (int off = 32; off > 0; off >>= 1) es += __shfl_xor(es, off);
  if (lane == 0) wsum[wid] = es;
  __syncthreads();
  const float esum = wsum[0] + wsum[1] + wsum[2] + wsum[3];

  for (int i = tid; i < N_; i += 256) s[i] = 0.f;
  __syncthreads();
  if (sel) s[myidx] = ev / esum;
  __syncthreads();
  for (int i = tid; i < N_; i += 256) rowp[i] = s[i];
}

// ==========================================================================
extern "C" void kernel_launch(void* const* d_in, const int* in_sizes, int n_in,
                              void* d_out, int out_size, void* d_ws,
                              size_t ws_size, hipStream_t stream)
{
  const float* X  = (const float*)d_in[0];
  const float* Wq = (const float*)d_in[1];
  const float* bq = (const float*)d_in[2];
  const float* Wk = (const float*)d_in[3];
  const float* bk = (const float*)d_in[4];
  float* out = (float*)d_out;

  const size_t qk = (size_t)M_ * DK_;
  const size_t f64_bytes  = qk * 8 * 2;
  const size_t bf_bytes   = qk * 2 * 2;
  const size_t base       = f64_bytes + bf_bytes;
  const size_t xdig_bytes = (size_t)M_ * D_ * NDIG;
  const size_t wdig_bytes = (size_t)512 * 1024 * NDIG;
  const size_t sbf_bytes  = (size_t)M_ * N_ * 2;
  const size_t oz_total = base + xdig_bytes + wdig_bytes;
  const size_t sc_total = base + sbf_bytes;
  if (ws_size < f64_bytes) return;

  double* Qd = (double*)d_ws;
  double* Kd = Qd + qk;
  ushort_t* Qbf = (ushort_t*)(Kd + qk);
  ushort_t* Kbf = Qbf + qk;
  char* region = (char*)d_ws + base;

  dim3 blk(256);
  if (ws_size >= oz_total) {
    signed char* Xdig = (signed char*)region;
    signed char* Wdig = Xdig + xdig_bytes;
    hipMemsetAsync(out, 0, (size_t)M_ * N_ * sizeof(float), stream);
    split_x_kernel<<<2048, blk, 0, stream>>>(X, Xdig);
    split_w_kernel<<<512, blk, 0, stream>>>(Wq, Wk, Wdig);
    ozaki_gemm_kernel<<<dim3(4, 256), dim3(512), 0, stream>>>(
        Xdig, Wdig, bq, bk, Qd, Kd, Qbf, Kbf);
    score_bf16_kernel<<<dim3(N_ / 128, N_ / 128, B_), blk, 0, stream>>>(
        Qbf, Kbf, out, (ushort_t*)region);           // digits dead now
    topk_scatter_kernel<<<dim3(M_), blk, 0, stream>>>(
        out, (ushort_t*)region, Qd, Kd, 2.5e-2f);
    return;
  }

  const bool bfpath = (ws_size >= base);
  const bool scpath = (ws_size >= sc_total);
  proj_kernel<<<dim3(4, 128), blk, 0, stream>>>(
      X, Wq, bq, Wk, bk, Qd, Kd, bfpath ? Qbf : (ushort_t*)nullptr,
      bfpath ? Kbf : (ushort_t*)nullptr);
  if (bfpath) {
    score_bf16_kernel<<<dim3(N_ / 128, N_ / 128, B_), blk, 0, stream>>>(
        Qbf, Kbf, out, scpath ? (ushort_t*)region : (ushort_t*)nullptr);
    if (scpath)
      topk_softmax_kernel<<<dim3(M_), blk, 0, stream>>>(
          out, (ushort_t*)region, (const float*)nullptr, Qd, Kd, 1.6e-2f);
    else
      topk_softmax_kernel<<<dim3(M_), blk, 0, stream>>>(
          out, (const ushort_t*)nullptr, out, Qd, Kd, 8e-3f);
  } else {
    score_f64_kernel<<<dim3(N_ / 64, N_ / 64, B_), blk, 0, stream>>>(Qd, Kd, out);
    topk_softmax_kernel<<<dim3(M_), blk, 0, stream>>>(
        out, (const ushort_t*)nullptr, out, Qd, Kd, 2.5e-4f);
  }
}

// Round 15
// 481.869 us; speedup vs baseline: 1.0632x; 1.0632x over previous
//
#include <hip/hip_runtime.h>
#include <cstdint>
#include <cstddef>

#define B_   8
#define N_   2048
#define D_   1024
#define DK_  256
#define M_   (B_ * N_)   // 16384
#define TOPK 32
#define NDIG 5

typedef unsigned short ushort_t;
typedef float  fvec4 __attribute__((ext_vector_type(4)));
typedef short  bvec8 __attribute__((ext_vector_type(8)));   // 8 bf16 (bits)
typedef float  avec4 __attribute__((ext_vector_type(4)));   // f32 MFMA acc
typedef int    ivec4 __attribute__((ext_vector_type(4)));   // 16B chunks / i32 acc

__device__ inline ushort_t f32_to_bf16_rn(float f) {
  unsigned u = __float_as_uint(f);
  u += 0x7fffu + ((u >> 16) & 1u);
  return (ushort_t)(u >> 16);
}
__device__ inline float bf16_to_f32(ushort_t u) {
  return __uint_as_float(((unsigned)u) << 16);
}
__device__ inline unsigned bf16_key(ushort_t h) {   // monotone 16-bit key
  return (h & 0x8000u) ? (unsigned)((~h) & 0xFFFFu) : (unsigned)(h | 0x8000u);
}
__device__ inline float key_to_f32(unsigned k) {    // exact inverse
  const ushort_t h = (k & 0x8000u) ? (ushort_t)(k ^ 0x8000u)
                                   : (ushort_t)((~k) & 0xFFFFu);
  return bf16_to_f32(h);
}

// ==========================================================================
// OZAKI PATH (r13, proven): exact integer decomposition on the i8 pipe.
// ==========================================================================
__global__ __launch_bounds__(256) void split_x_kernel(
    const float* __restrict__ X, signed char* __restrict__ Xdig)
{
  const size_t MK = (size_t)M_ * D_;
  const int total = (int)(MK / 4);
  for (int idx = blockIdx.x * 256 + threadIdx.x; idx < total;
       idx += gridDim.x * 256) {
    const fvec4 x = ((const fvec4*)X)[idx];
    unsigned pack[NDIG] = {0u, 0u, 0u, 0u, 0u};
#pragma unroll
    for (int e = 0; e < 4; e++) {
      float s = x[e] * 0.0625f * 128.f;
#pragma unroll
      for (int d = 0; d < NDIG; d++) {
        const float a = rintf(s);
        s = (s - a) * 128.f;
        pack[d] |= ((unsigned)((int)a & 0xff)) << (e * 8);
      }
    }
#pragma unroll
    for (int d = 0; d < NDIG; d++)
      ((unsigned*)(Xdig + (size_t)d * MK))[idx] = pack[d];
  }
}

__global__ __launch_bounds__(256) void split_w_kernel(
    const float* __restrict__ Wq, const float* __restrict__ Wk,
    signed char* __restrict__ Wdig)
{
  const size_t WK = (size_t)512 * 1024;
  const int cc = blockIdx.x;
  const float* Wp = (cc < 256) ? Wq : Wk;
  const int c = cc & 255;
  const int k0 = threadIdx.x * 4;
  unsigned pack[NDIG] = {0u, 0u, 0u, 0u, 0u};
#pragma unroll
  for (int e = 0; e < 4; e++) {
    float s = Wp[(size_t)(k0 + e) * DK_ + c] * 16.f * 128.f;
#pragma unroll
    for (int d = 0; d < NDIG; d++) {
      const float a = rintf(s);
      s = (s - a) * 128.f;
      pack[d] |= ((unsigned)((int)a & 0xff)) << (e * 8);
    }
  }
#pragma unroll
  for (int d = 0; d < NDIG; d++)
    ((unsigned*)(Wdig + (size_t)d * WK + (size_t)cc * 1024))[threadIdx.x] = pack[d];
}

__global__ __launch_bounds__(512) void ozaki_gemm_kernel(
    const signed char* __restrict__ Xdig, const signed char* __restrict__ Wdig,
    const float* __restrict__ bq, const float* __restrict__ bk,
    double* __restrict__ Qd, double* __restrict__ Kd,
    ushort_t* __restrict__ Qbf, ushort_t* __restrict__ Kbf)
{
  __shared__ __align__(16) char L[61440];
  const int tid  = threadIdx.x;
  const int lane = tid & 63;
  const int w    = tid >> 6;
  const int wm   = (w >> 2) * 32;
  const int wc   = (w & 3) * 32;
  const int m0   = blockIdx.y * 64;
  const int c0   = blockIdx.x * 128;
  const size_t MK = (size_t)M_ * D_;
  const size_t WK = (size_t)512 * 1024;

  ivec4 acc[NDIG][2][2];
#pragma unroll
  for (int s = 0; s < NDIG; s++)
#pragma unroll
    for (int mi = 0; mi < 2; mi++)
#pragma unroll
      for (int nj = 0; nj < 2; nj++) acc[s][mi][nj] = (ivec4)(0);

  for (int k0 = 0; k0 < D_; k0 += 64) {
    for (int c = tid; c < 1280; c += 512) {
      const int d = c >> 8, rem = c & 255, r = rem >> 2, kp = rem & 3;
      const ivec4 raw = *(const ivec4*)(Xdig + (size_t)d * MK +
                         (size_t)(m0 + r) * D_ + k0 + kp * 16);
      *(ivec4*)&L[d * 4096 + r * 64 + ((kp ^ (r & 3)) << 4)] = raw;
    }
    for (int c = tid; c < 2560; c += 512) {
      const int d = c >> 9, rem = c & 511, r = rem >> 2, kp = rem & 3;
      const ivec4 raw = *(const ivec4*)(Wdig + (size_t)d * WK +
                         (size_t)(c0 + r) * 1024 + k0 + kp * 16);
      *(ivec4*)&L[20480 + d * 8192 + r * 64 + ((kp ^ (r & 3)) << 4)] = raw;
    }
    __syncthreads();

    ivec4 afr[2][NDIG];
#pragma unroll
    for (int mi = 0; mi < 2; mi++) {
      const int r = wm + mi * 16 + (lane & 15);
      const int sl = (((lane >> 4) ^ (r & 3)) << 4);
#pragma unroll
      for (int d = 0; d < NDIG; d++)
        afr[mi][d] = *(const ivec4*)&L[d * 4096 + r * 64 + sl];
    }
#pragma unroll
    for (int nj = 0; nj < 2; nj++) {
      const int rc = wc + nj * 16 + (lane & 15);
      const int sl = (((lane >> 4) ^ (rc & 3)) << 4);
#pragma unroll
      for (int jd = 0; jd < NDIG; jd++) {
        const ivec4 bfr = *(const ivec4*)&L[20480 + jd * 8192 + rc * 64 + sl];
#pragma unroll
        for (int id = 0; id + jd < NDIG; id++)
#pragma unroll
          for (int mi = 0; mi < 2; mi++)
            acc[id + jd][mi][nj] = __builtin_amdgcn_mfma_i32_16x16x64_i8(
                afr[mi][id], bfr, acc[id + jd][mi][nj], 0, 0, 0);
      }
    }
    __syncthreads();
  }

  const double SCL[NDIG] = {0x1p-14, 0x1p-21, 0x1p-28, 0x1p-35, 0x1p-42};
#pragma unroll
  for (int nj = 0; nj < 2; nj++) {
    const int c = c0 + wc + nj * 16 + (lane & 15);
    const bool isQ = (c < 256);
    const int cw = isQ ? c : (c - 256);
    const double bias = (double)(isQ ? bq[cw] : bk[cw]);
#pragma unroll
    for (int mi = 0; mi < 2; mi++) {
#pragma unroll
      for (int ri = 0; ri < 4; ri++) {
        const int m = m0 + wm + mi * 16 + (lane >> 4) * 4 + ri;
        double val = bias;
#pragma unroll
        for (int s = 0; s < NDIG; s++)
          val += (double)acc[s][mi][nj][ri] * SCL[s];
        const size_t off = (size_t)m * DK_ + cw;
        if (isQ) { Qd[off] = val; Qbf[off] = f32_to_bf16_rn((float)val); }
        else     { Kd[off] = val; Kbf[off] = f32_to_bf16_rn((float)val); }
      }
    }
  }
}

// ==========================================================================
// FALLBACK proj (r5, proven) — unchanged.
// ==========================================================================
__global__ __launch_bounds__(256) void proj_kernel(
    const float* __restrict__ X, const float* __restrict__ Wq,
    const float* __restrict__ bq, const float* __restrict__ Wk,
    const float* __restrict__ bk, double* __restrict__ Qd,
    double* __restrict__ Kd, ushort_t* __restrict__ Qbf,
    ushort_t* __restrict__ Kbf)
{
  __shared__ float As[16][132];
  __shared__ float Bs[16][132];
  const int tid = threadIdx.x;
  const int tx = tid & 15;
  const int ty = tid >> 4;
  const int m0 = blockIdx.y * 128;
  const int j0 = blockIdx.x * 128;
  const bool isQ = (j0 < 256);
  const float* Wp = isQ ? Wq : Wk;
  const float* bp = isQ ? bq : bk;
  const int jw = isQ ? j0 : (j0 - 256);

  double acc[8][8];
#pragma unroll
  for (int i = 0; i < 8; i++)
#pragma unroll
    for (int j = 0; j < 8; j++) acc[i][j] = 0.0;

  for (int k0 = 0; k0 < D_; k0 += 16) {
    {
      const int r = tid >> 2, k4 = (tid & 3) * 4;
#pragma unroll
      for (int p = 0; p < 2; p++) {
        const int m = r + 64 * p;
        const fvec4 v = *(const fvec4*)&X[(size_t)(m0 + m) * D_ + k0 + k4];
#pragma unroll
        for (int c = 0; c < 4; c++) As[k4 + c][m] = v[c];
      }
    }
    {
      const int k = tid >> 4, j8 = (tid & 15) * 8;
      const fvec4 v0 = *(const fvec4*)&Wp[(size_t)(k0 + k) * DK_ + jw + j8];
      const fvec4 v1 = *(const fvec4*)&Wp[(size_t)(k0 + k) * DK_ + jw + j8 + 4];
      *(fvec4*)&Bs[k][j8]     = v0;
      *(fvec4*)&Bs[k][j8 + 4] = v1;
    }
    __syncthreads();
#pragma unroll
    for (int kk = 0; kk < 16; kk++) {
      const fvec4 a0 = *(const fvec4*)&As[kk][ty * 8];
      const fvec4 a1 = *(const fvec4*)&As[kk][ty * 8 + 4];
      const fvec4 b0 = *(const fvec4*)&Bs[kk][tx * 8];
      const fvec4 b1 = *(const fvec4*)&Bs[kk][tx * 8 + 4];
      double a[8], b[8];
#pragma unroll
      for (int i = 0; i < 4; i++) {
        a[i] = (double)a0[i]; a[i + 4] = (double)a1[i];
        b[i] = (double)b0[i]; b[i + 4] = (double)b1[i];
      }
#pragma unroll
      for (int i = 0; i < 8; i++)
#pragma unroll
        for (int j = 0; j < 8; j++)
          acc[i][j] = fma(a[i], b[j], acc[i][j]);
    }
    __syncthreads();
  }

#pragma unroll
  for (int i = 0; i < 8; i++) {
    const int m = m0 + ty * 8 + i;
#pragma unroll
    for (int j = 0; j < 8; j++) {
      const int c = jw + tx * 8 + j;
      const double v = acc[i][j] + (double)bp[c];
      const size_t off = (size_t)m * DK_ + c;
      if (isQ) { Qd[off] = v; if (Qbf) Qbf[off] = f32_to_bf16_rn((float)v); }
      else     { Kd[off] = v; if (Kbf) Kbf[off] = f32_to_bf16_rn((float)v); }
    }
  }
}

// ==========================================================================
// scores via bf16 MFMA (proven). When outbf is set AND outf is set, also
// zero-fills the out tile (coalesced) so no separate memset is needed.
// ==========================================================================
__global__ __launch_bounds__(256) void score_bf16_kernel(
    const ushort_t* __restrict__ Qb, const ushort_t* __restrict__ Kb,
    float* __restrict__ outf, ushort_t* __restrict__ outbf)
{
  __shared__ ushort_t Asl[128 * 40];
  __shared__ ushort_t Bsl[128 * 40];
  const int tid = threadIdx.x;
  const int b  = blockIdx.z;
  const int q0 = blockIdx.y * 128;
  const int m0 = blockIdx.x * 128;
  const int w = tid >> 6, lane = tid & 63;
  const int wq = (w >> 1) * 64, wm = (w & 1) * 64;
  const int rsel = lane & 15, ksel = (lane >> 4) * 8;

  // zero-fill out tile (oz path): coalesced fvec4 stores, overlaps compute
  if (outf && outbf) {
    const fvec4 z = (fvec4)(0.f);
    for (int i = tid; i < 4096; i += 256) {
      const int r = i >> 5, c4 = i & 31;
      *(fvec4*)&outf[((size_t)b * N_ + q0 + r) * N_ + m0 + c4 * 4] = z;
    }
  }

  avec4 acc[4][4];
#pragma unroll
  for (int i = 0; i < 4; i++)
#pragma unroll
    for (int j = 0; j < 4; j++) acc[i][j] = (avec4)(0.f);

  for (int k0 = 0; k0 < DK_; k0 += 32) {
#pragma unroll
    for (int cc = 0; cc < 2; cc++) {
      const int c = tid + cc * 256;
      const int r = c >> 2, part = c & 3;
      const ivec4 va = *(const ivec4*)&Qb[((size_t)b * N_ + q0 + r) * DK_ + k0 + part * 8];
      const ivec4 vb = *(const ivec4*)&Kb[((size_t)b * N_ + m0 + r) * DK_ + k0 + part * 8];
      *(ivec4*)&Asl[r * 40 + part * 8] = va;
      *(ivec4*)&Bsl[r * 40 + part * 8] = vb;
    }
    __syncthreads();
    bvec8 aF[4], bF[4];
#pragma unroll
    for (int mi = 0; mi < 4; mi++)
      aF[mi] = *(const bvec8*)&Asl[(wq + mi * 16 + rsel) * 40 + ksel];
#pragma unroll
    for (int nj = 0; nj < 4; nj++)
      bF[nj] = *(const bvec8*)&Bsl[(wm + nj * 16 + rsel) * 40 + ksel];
#pragma unroll
    for (int mi = 0; mi < 4; mi++)
#pragma unroll
      for (int nj = 0; nj < 4; nj++)
        acc[mi][nj] = __builtin_amdgcn_mfma_f32_16x16x32_bf16(
            aF[mi], bF[nj], acc[mi][nj], 0, 0, 0);
    __syncthreads();
  }

#pragma unroll
  for (int mi = 0; mi < 4; mi++)
#pragma unroll
    for (int nj = 0; nj < 4; nj++)
#pragma unroll
      for (int r = 0; r < 4; r++) {
        const int row = q0 + wq + mi * 16 + (lane >> 4) * 4 + r;
        const int col = m0 + wm + nj * 16 + (lane & 15);
        const size_t off = ((size_t)b * N_ + row) * N_ + col;
        const float v = acc[mi][nj][r] * 0.0625f;
        if (outbf) outbf[off] = f32_to_bf16_rn(v);
        else       outf[off] = v;
      }
}

// f32 scores from f64 (deep fallback) — unchanged.
__global__ __launch_bounds__(256) void score_f64_kernel(
    const double* __restrict__ Qd, const double* __restrict__ Kd,
    float* __restrict__ out)
{
  __shared__ float As[16][68];
  __shared__ float Bs[16][68];
  const int tid = threadIdx.x;
  const int tx = tid & 15, ty = tid >> 4;
  const int b  = blockIdx.z;
  const int q0 = blockIdx.y * 64;
  const int m0 = blockIdx.x * 64;
  const size_t rowbase = (size_t)b * N_;

  float acc[4][4];
#pragma unroll
  for (int i = 0; i < 4; i++)
#pragma unroll
    for (int j = 0; j < 4; j++) acc[i][j] = 0.f;

  for (int k0 = 0; k0 < DK_; k0 += 16) {
    const int mt = tid >> 4, kt = tid & 15;
#pragma unroll
    for (int p = 0; p < 4; p++) {
      const int m = mt + 16 * p;
      As[kt][m] = (float)Qd[(rowbase + q0 + m) * DK_ + k0 + kt];
      Bs[kt][m] = (float)Kd[(rowbase + m0 + m) * DK_ + k0 + kt];
    }
    __syncthreads();
#pragma unroll
    for (int kk = 0; kk < 16; kk++) {
      float a[4], bb[4];
#pragma unroll
      for (int i = 0; i < 4; i++) a[i] = As[kk][ty * 4 + i];
#pragma unroll
      for (int j = 0; j < 4; j++) bb[j] = Bs[kk][tx * 4 + j];
#pragma unroll
      for (int i = 0; i < 4; i++)
#pragma unroll
        for (int j = 0; j < 4; j++)
          acc[i][j] = fmaf(a[i], bb[j], acc[i][j]);
    }
    __syncthreads();
  }

#pragma unroll
  for (int i = 0; i < 4; i++) {
    const size_t r = (size_t)b * N_ + q0 + ty * 4 + i;
#pragma unroll
    for (int j = 0; j < 4; j++)
      out[r * N_ + m0 + tx * 4 + j] = acc[i][j] * 0.0625f;
  }
}

// ==========================================================================
// topk (oz path): binary-search selection + LATENCY-OPTIMIZED rescore
// (16 lanes/candidate -> 16 in flight, ~3 rounds; qreg in registers from
// global; 1 barrier/search iter). Scatter-only output (out pre-zeroed by
// score kernel). Margin 1.6e-2 (r11-r13 proven level).
// ==========================================================================
__global__ __launch_bounds__(256) void topk_scatter_kernel(
    float* __restrict__ out, const ushort_t* __restrict__ sbf,
    const double* __restrict__ Qd, const double* __restrict__ Kd,
    float margin)
{
  const int bid = blockIdx.x;
  const int row = (bid & 7) * 2048 + (bid >> 3);   // batch-per-XCD locality
  const int b   = row >> 11;
  const int tid = threadIdx.x;
  const int lane = tid & 63, wid = tid >> 6;
  const int grp = tid >> 4, l4 = tid & 15;         // 16 groups of 16 lanes

  __shared__ int      cidx[128];
  __shared__ double   cval[128];
  __shared__ int      cnt_ws[2][4];
  __shared__ int      ncand_s;
  __shared__ double   wmax[4];
  __shared__ float    wsum[4];

  // ---- load 8 scores into registers (one 16B load) ----
  const ivec4 v = *(const ivec4*)&sbf[(size_t)row * N_ + tid * 8];
  const ushort_t* u = (const ushort_t*)&v;
  unsigned kk[8];
  float    fv[8];
#pragma unroll
  for (int e = 0; e < 8; e++) {
    kk[e] = bf16_key(u[e]);
    fv[e] = bf16_to_f32(u[e]);
  }
  // ---- my 16-double slice of Q row (coalesced global, held in regs) ----
  double qreg[16];
#pragma unroll
  for (int q = 0; q < 16; q++)
    qreg[q] = Qd[(size_t)row * DK_ + q * 16 + l4];
  if (tid == 0) ncand_s = 0;

  // ---- binary search for 32nd-largest stored key (1 barrier/iter) ----
  unsigned lo = 0, hi = 65535;
#pragma unroll 1
  for (int it = 0; it < 16; it++) {
    const unsigned mid = (lo + hi + 1) >> 1;
    int c = 0;
#pragma unroll
    for (int e = 0; e < 8; e++) c += (kk[e] >= mid);
#pragma unroll
    for (int off = 32; off > 0; off >>= 1) c += __shfl_xor(c, off);
    if (lane == 0) cnt_ws[it & 1][wid] = c;
    __syncthreads();
    const int tot = cnt_ws[it & 1][0] + cnt_ws[it & 1][1] +
                    cnt_ws[it & 1][2] + cnt_ws[it & 1][3];
    if (tot >= TOPK) lo = mid; else hi = mid - 1;
  }
  const float cthr = key_to_f32(lo) - margin;   // exact 32nd stored value

  // ---- gather candidates ----
#pragma unroll
  for (int e = 0; e < 8; e++) {
    if (fv[e] >= cthr) {
      const int p = atomicAdd(&ncand_s, 1);
      if (p < 128) cidx[p] = tid * 8 + e;
    }
  }
  __syncthreads();
  int nc = ncand_s;
  if (nc > 128) nc = 128;

  // ---- f64 rescore: 16 lanes per candidate, 16 candidates in flight ----
  for (int base = 0; base < nc; base += 16) {
    const int c = base + grp;
    if (c < nc) {
      const double* kp = Kd + ((size_t)b * N_ + cidx[c]) * DK_;
      double a = 0.0;
#pragma unroll
      for (int q = 0; q < 16; q++)
        a = fma(qreg[q], kp[q * 16 + l4], a);     // coalesced per group
#pragma unroll
      for (int off = 1; off < 16; off <<= 1) a += __shfl_xor(a, off);
      if (l4 == 0) cval[c] = a * 0.0625;
    }
  }
  __syncthreads();

  // ---- exact top-32 (value desc, index asc) + softmax + scatter ----
  bool sel = false;
  double vv = 0.0;
  int myidx = 0;
  if (tid < nc) {
    vv = cval[tid];
    myidx = cidx[tid];
    int rank = 0;
    for (int j = 0; j < nc; j++) {
      const double vj = cval[j];
      rank += (vj > vv) || (vj == vv && cidx[j] < myidx);
    }
    sel = (rank < TOPK);
  }
  double mv = (tid < nc) ? vv : -1.0e300;
#pragma unroll
  for (int off = 32; off > 0; off >>= 1) {
    const double o = __shfl_xor(mv, off);
    mv = o > mv ? o : mv;
  }
  if (lane == 0) wmax[wid] = mv;
  __syncthreads();
  const double vmax = max(max(wmax[0], wmax[1]), max(wmax[2], wmax[3]));
  const float ev = sel ? expf((float)(vv - vmax)) : 0.f;
  float es = ev;
#pragma unroll
  for (int off = 32; off > 0; off >>= 1) es += __shfl_xor(es, off);
  if (lane == 0) wsum[wid] = es;
  __syncthreads();
  const float esum = wsum[0] + wsum[1] + wsum[2] + wsum[3];

  if (sel) out[(size_t)row * N_ + myidx] = ev / esum;
}

// ==========================================================================
// FULL topk (fallback tiers; scores may live in `out`) — r13 version.
// ==========================================================================
__global__ __launch_bounds__(256) void topk_softmax_kernel(
    float* __restrict__ out, const ushort_t* __restrict__ sbf,
    const float* __restrict__ sf, const double* __restrict__ Qd,
    const double* __restrict__ Kd, float margin)
{
  const int row = blockIdx.x;
  const int b   = row >> 11;
  const int tid = threadIdx.x;
  float* rowp = out + (size_t)row * N_;

  __shared__ float    s[N_];
  __shared__ double   qrow[DK_];
  __shared__ unsigned hist[256];
  __shared__ unsigned sfx[256];
  __shared__ int      cidx[128];
  __shared__ double   cval[128];
  __shared__ int      ncand_s;
  __shared__ unsigned prefix_s;
  __shared__ int      want_s;
  __shared__ double   wmax[4];
  __shared__ float    wsum[4];

  if (sbf) {
    const ivec4 v = *(const ivec4*)&sbf[(size_t)row * N_ + tid * 8];
    const ushort_t* u = (const ushort_t*)&v;
#pragma unroll
    for (int c = 0; c < 8; c++) s[tid * 8 + c] = bf16_to_f32(u[c]);
  } else {
#pragma unroll
    for (int p = 0; p < 2; p++) {
      const fvec4 v = *(const fvec4*)&sf[(size_t)row * N_ + tid * 8 + p * 4];
#pragma unroll
      for (int c = 0; c < 4; c++) s[tid * 8 + p * 4 + c] = v[c];
    }
  }
  qrow[tid] = Qd[(size_t)row * DK_ + tid];
  __syncthreads();

  unsigned prefix = 0;
  int want = TOPK;
  for (int pass = 0; pass < 2; pass++) {
    hist[tid] = 0;
    __syncthreads();
    const int shift_b = 8 - 8 * pass;
    for (int i = tid; i < N_; i += 256) {
      unsigned uu = __float_as_uint(s[i]);
      uu = (uu & 0x80000000u) ? ~uu : (uu | 0x80000000u);
      const unsigned key = uu >> 16;
      const bool ok = (pass == 0) || ((key >> 8) == prefix);
      if (ok) atomicAdd(&hist[(key >> shift_b) & 255u], 1u);
    }
    __syncthreads();
    sfx[tid] = hist[tid];
    __syncthreads();
    for (int st = 1; st < 256; st <<= 1) {
      const unsigned add = (tid + st < 256) ? sfx[tid + st] : 0u;
      __syncthreads();
      sfx[tid] += add;
      __syncthreads();
    }
    const int gt = (int)(sfx[tid] - hist[tid]);
    if (gt < want && (int)sfx[tid] >= want) {
      prefix_s = (prefix << 8) | (unsigned)tid;
      want_s = want - gt;
    }
    __syncthreads();
    prefix = prefix_s;
    want = want_s;
    __syncthreads();
  }
  const unsigned k16 = prefix;
  unsigned ulo;
  if (k16 & 0x8000u) ulo = (k16 << 16) ^ 0x80000000u;
  else               ulo = ~(k16 << 16);
  const float cthr = __uint_as_float(ulo) - margin;

  if (tid == 0) ncand_s = 0;
  __syncthreads();
  for (int i = tid; i < N_; i += 256) {
    if (s[i] >= cthr) {
      const int p = atomicAdd(&ncand_s, 1);
      if (p < 128) cidx[p] = i;
    }
  }
  __syncthreads();
  int nc = ncand_s;
  if (nc > 128) nc = 128;

  const int wid = tid >> 6, lane = tid & 63;
  for (int base = 0; base < nc; base += 4) {
    const int c = base + wid;
    if (c < nc) {
      const double* kp = Kd + ((size_t)b * N_ + cidx[c]) * DK_;
      double a = 0.0;
#pragma unroll
      for (int q = 0; q < 4; q++)
        a = fma(qrow[lane * 4 + q], kp[lane * 4 + q], a);
#pragma unroll
      for (int off = 32; off > 0; off >>= 1) a += __shfl_xor(a, off);
      if (lane == 0) cval[c] = a * 0.0625;
    }
  }
  __syncthreads();

  bool sel = false;
  double v = 0.0;
  int myidx = 0;
  if (tid < nc) {
    v = cval[tid];
    myidx = cidx[tid];
    int rank = 0;
    for (int j = 0; j < nc; j++) {
      const double vj = cval[j];
      rank += (vj > v) || (vj == v && cidx[j] < myidx);
    }
    sel = (rank < TOPK);
  }
  double mv = (tid < nc) ? v : -1.0e300;
#pragma unroll
  for (int off = 32; off > 0; off >>= 1) {
    const double o = __shfl_xor(mv, off);
    mv = o > mv ? o : mv;
  }
  if (lane == 0) wmax[wid] = mv;
  __syncthreads();
  const double vmax = max(max(wmax[0], wmax[1]), max(wmax[2], wmax[3]));
  const float ev = sel ? expf((float)(v - vmax)) : 0.f;
  float es = ev;
#pragma unroll
  for (int off = 32; off > 0; off >>= 1) es += __shfl_xor(es, off);
  if (lane == 0) wsum[wid] = es;
  __syncthreads();
  const float esum = wsum[0] + wsum[1] + wsum[2] + wsum[3];

  for (int i = tid; i < N_; i += 256) s[i] = 0.f;
  __syncthreads();
  if (sel) s[myidx] = ev / esum;
  __syncthreads();
  for (int i = tid; i < N_; i += 256) rowp[i] = s[i];
}

// ==========================================================================
extern "C" void kernel_launch(void* const* d_in, const int* in_sizes, int n_in,
                              void* d_out, int out_size, void* d_ws,
                              size_t ws_size, hipStream_t stream)
{
  const float* X  = (const float*)d_in[0];
  const float* Wq = (const float*)d_in[1];
  const float* bq = (const float*)d_in[2];
  const float* Wk = (const float*)d_in[3];
  const float* bk = (const float*)d_in[4];
  float* out = (float*)d_out;

  const size_t qk = (size_t)M_ * DK_;
  const size_t f64_bytes  = qk * 8 * 2;
  const size_t bf_bytes   = qk * 2 * 2;
  const size_t base       = f64_bytes + bf_bytes;
  const size_t xdig_bytes = (size_t)M_ * D_ * NDIG;
  const size_t wdig_bytes = (size_t)512 * 1024 * NDIG;
  const size_t sbf_bytes  = (size_t)M_ * N_ * 2;
  const size_t oz_total = base + xdig_bytes + wdig_bytes;
  const size_t sc_total = base + sbf_bytes;
  if (ws_size < f64_bytes) return;

  double* Qd = (double*)d_ws;
  double* Kd = Qd + qk;
  ushort_t* Qbf = (ushort_t*)(Kd + qk);
  ushort_t* Kbf = Qbf + qk;
  char* region = (char*)d_ws + base;

  dim3 blk(256);
  if (ws_size >= oz_total) {
    signed char* Xdig = (signed char*)region;
    signed char* Wdig = Xdig + xdig_bytes;
    split_x_kernel<<<2048, blk, 0, stream>>>(X, Xdig);
    split_w_kernel<<<512, blk, 0, stream>>>(Wq, Wk, Wdig);
    ozaki_gemm_kernel<<<dim3(4, 256), dim3(512), 0, stream>>>(
        Xdig, Wdig, bq, bk, Qd, Kd, Qbf, Kbf);
    score_bf16_kernel<<<dim3(N_ / 128, N_ / 128, B_), blk, 0, stream>>>(
        Qbf, Kbf, out, (ushort_t*)region);   // writes Sbf + zero-fills out
    topk_scatter_kernel<<<dim3(M_), blk, 0, stream>>>(
        out, (ushort_t*)region, Qd, Kd, 1.6e-2f);
    return;
  }

  const bool bfpath = (ws_size >= base);
  const bool scpath = (ws_size >= sc_total);
  proj_kernel<<<dim3(4, 128), blk, 0, stream>>>(
      X, Wq, bq, Wk, bk, Qd, Kd, bfpath ? Qbf : (ushort_t*)nullptr,
      bfpath ? Kbf : (ushort_t*)nullptr);
  if (bfpath) {
    score_bf16_kernel<<<dim3(N_ / 128, N_ / 128, B_), blk, 0, stream>>>(
        Qbf, Kbf, scpath ? (float*)nullptr : out,
        scpath ? (ushort_t*)region : (ushort_t*)nullptr);
    if (scpath)
      topk_softmax_kernel<<<dim3(M_), blk, 0, stream>>>(
          out, (ushort_t*)region, (const float*)nullptr, Qd, Kd, 1.6e-2f);
    else
      topk_softmax_kernel<<<dim3(M_), blk, 0, stream>>>(
          out, (const ushort_t*)nullptr, out, Qd, Kd, 8e-3f);
  } else {
    score_f64_kernel<<<dim3(N_ / 64, N_ / 64, B_), blk, 0, stream>>>(Qd, Kd, out);
    topk_softmax_kernel<<<dim3(M_), blk, 0, stream>>>(
        out, (const ushort_t*)nullptr, out, Qd, Kd, 2.5e-4f);
  }
}